// Round 4
// baseline (110.809 us; speedup 1.0000x reference)
//
#include <hip/hip_runtime.h>

#define CIN  32
#define OCH  64
#define HH   56
#define WW   56
#define BB   4
#define OT   4                 // output channels per thread/block
#define IMG  (HH * WW)         // 3136
#define NW   18432             // 64*32*3*3
#define NWR  18                // 1152 weights per o-tile / 64 lanes

__global__ __launch_bounds__(256) void absmean_reduce(const float* __restrict__ w,
                                                      float* __restrict__ ws) {
    int idx = (blockIdx.x * 256 + threadIdx.x) * 4;   // 18 blocks * 256 * 4 = 18432
    float4 v = *reinterpret_cast<const float4*>(w + idx);
    float s = fabsf(v.x) + fabsf(v.y) + fabsf(v.z) + fabsf(v.w);
    #pragma unroll
    for (int off = 32; off > 0; off >>= 1)
        s += __shfl_down(s, off);
    __shared__ float smem[4];
    int lane = threadIdx.x & 63, wv = threadIdx.x >> 6;
    if (lane == 0) smem[wv] = s;
    __syncthreads();
    if (threadIdx.x == 0)
        atomicAdd(ws, smem[0] + smem[1] + smem[2] + smem[3]);
}

// block = 64 threads (1 wave) = 64 pixels of one (b, o-tile) image.
// Weights: each lane caches 18 of the o-tile's 1152 weights in VGPRs
// (coalesced one-time load); the fully-unrolled channel loop broadcasts
// them with v_readlane (compile-time lane index) -> zero per-channel VMEM.
__global__ __launch_bounds__(64) void minconv_kernel(const float* __restrict__ x,
                                                     const float* __restrict__ wts,
                                                     const float* __restrict__ ws,
                                                     float* __restrict__ out) {
    const int lane = threadIdx.x;
    const int hw = blockIdx.x * 64 + lane;          // 0..3135, exact
    const int o0 = blockIdx.y * OT;
    const int b  = blockIdx.z;
    const int h  = hw / WW;
    const int w  = hw - h * WW;

    // one-time coalesced weight cache: wreg[j] on lane L = wb[j*64+L]
    const float* wb = wts + o0 * (CIN * 9);
    float wreg[NWR];
    #pragma unroll
    for (int j = 0; j < NWR; ++j)
        wreg[j] = wb[j * 64 + lane];

    // 9 clamped tap offsets + validity masks (zero-pad semantics)
    int  rel[9];
    bool msk[9];
    #pragma unroll
    for (int kh = 0; kh < 3; ++kh) {
        int hh = h - 1 + kh;
        bool vh = (unsigned)hh < (unsigned)HH;
        int hc = min(max(hh, 0), HH - 1);
        #pragma unroll
        for (int kw = 0; kw < 3; ++kw) {
            int wwc = w - 1 + kw;
            bool vw = (unsigned)wwc < (unsigned)WW;
            rel[kh * 3 + kw] = hc * WW + min(max(wwc, 0), WW - 1);
            msk[kh * 3 + kw] = vh && vw;
        }
    }

    const float* xb = x + b * (CIN * IMG);          // block-uniform base (SGPR)

    float acc[OT] = {0.f, 0.f, 0.f, 0.f};
    float xv[2][9];
    #pragma unroll
    for (int t = 0; t < 9; ++t)                     // prefetch channel 0
        xv[0][t] = xb[rel[t]];

    #pragma unroll
    for (int c = 0; c < CIN; ++c) {
        const int cur = c & 1, nxt = cur ^ 1;
        if (c + 1 < CIN) {                          // prefetch next channel
            const float* xc = xb + (c + 1) * IMG;
            #pragma unroll
            for (int t = 0; t < 9; ++t)
                xv[nxt][t] = xc[rel[t]];
        }
        float xm[9];
        #pragma unroll
        for (int t = 0; t < 9; ++t)
            xm[t] = msk[t] ? xv[cur][t] : 0.f;

        #pragma unroll
        for (int oo = 0; oo < OT; ++oo) {
            #pragma unroll
            for (int t = 0; t < 9; ++t) {
                const int idx = (oo * CIN + c) * 9 + t;        // compile-time
                float wv = __uint_as_float(
                    __builtin_amdgcn_readlane(__float_as_uint(wreg[idx >> 6]),
                                              idx & 63));
                acc[oo] += fminf(xm[t], wv);
            }
        }
    }

    const float mu = ws[0] * (1.0f / (float)NW);
    float* ob = out + (b * OCH + o0) * IMG + hw;
    #pragma unroll
    for (int oo = 0; oo < OT; ++oo)
        ob[oo * IMG] = mu * acc[oo];
}

extern "C" void kernel_launch(void* const* d_in, const int* in_sizes, int n_in,
                              void* d_out, int out_size, void* d_ws, size_t ws_size,
                              hipStream_t stream) {
    const float* x   = (const float*)d_in[0];   // 4*32*56*56
    const float* w   = (const float*)d_in[1];   // 64*32*3*3
    float*       out = (float*)d_out;           // 4*64*56*56
    float*       ws  = (float*)d_ws;

    hipMemsetAsync(ws, 0, sizeof(float), stream);
    absmean_reduce<<<NW / (256 * 4), 256, 0, stream>>>(w, ws);
    dim3 grid(IMG / 64, OCH / OT, BB);          // 49 x 16 x 4 = 3136 blocks
    minconv_kernel<<<grid, 64, 0, stream>>>(x, w, ws, out);
}

// Round 5
// 95.027 us; speedup vs baseline: 1.1661x; 1.1661x over previous
//
#include <hip/hip_runtime.h>

#define CIN  32
#define OCH  64
#define HH   56
#define WW   56
#define BB   4
#define OT   4                  // output channels per block
#define TH   8                  // output rows per block strip
#define NT   448                // threads = 8*56, 7 waves, zero waste
#define CG   8                  // channels per LDS phase
#define HALO_H (TH + 2)         // 10
#define HALO_W (WW + 2)         // 58
#define CH_STRIDE (HALO_H * HALO_W)   // 580
#define STAGE (CG * CH_STRIDE)        // 4640
#define IMG  (HH * WW)          // 3136
#define NW   18432              // 64*32*3*3

__global__ __launch_bounds__(256) void absmean_reduce(const float* __restrict__ w,
                                                      float* __restrict__ ws) {
    int idx = (blockIdx.x * 256 + threadIdx.x) * 4;   // 18 blocks * 256 * 4 = 18432
    float4 v = *reinterpret_cast<const float4*>(w + idx);
    float s = fabsf(v.x) + fabsf(v.y) + fabsf(v.z) + fabsf(v.w);
    #pragma unroll
    for (int off = 32; off > 0; off >>= 1)
        s += __shfl_down(s, off);
    __shared__ float smem[4];
    int lane = threadIdx.x & 63, wv = threadIdx.x >> 6;
    if (lane == 0) smem[wv] = s;
    __syncthreads();
    if (threadIdx.x == 0)
        atomicAdd(ws, smem[0] + smem[1] + smem[2] + smem[3]);
}

// Block = 448 threads = one 8x56 output strip (100% lane use, no masks).
// x staged zero-padded in LDS (8 ch/phase); weights read at wave-uniform
// addresses in fully uniform control flow -> scalar loads (SGPR operands
// feed v_min_f32 directly).
__global__ __launch_bounds__(NT) void minconv_kernel(const float* __restrict__ x,
                                                     const float* __restrict__ wts,
                                                     const float* __restrict__ ws,
                                                     float* __restrict__ out) {
    __shared__ float xs[STAGE];         // 18560 B

    const int tid = threadIdx.x;
    const int ht  = blockIdx.x;         // 0..6
    const int o0  = blockIdx.y * OT;    // 0..60
    const int b   = blockIdx.z;         // 0..3
    const int h0  = ht * TH;

    const int ph = tid / WW;            // 0..7
    const int pw = tid - ph * WW;       // 0..55

    const float* xb = x + b * (CIN * IMG);
    const float* wb = wts + o0 * (CIN * 9);

    float acc[OT] = {0.f, 0.f, 0.f, 0.f};

    for (int cg = 0; cg < CIN; cg += CG) {
        __syncthreads();                // protect previous phase's reads
        const float* xc = xb + cg * IMG;
        for (int j = 0; j < 11; ++j) {  // ceil(4640/448)
            int i = tid + j * NT;
            if (i < STAGE) {
                int c  = i / CH_STRIDE;
                int r  = (i - c * CH_STRIDE) / HALO_W;
                int cc = i - c * CH_STRIDE - r * HALO_W;
                int gh = h0 - 1 + r;
                int gw = cc - 1;
                float v = 0.f;
                if ((unsigned)gh < (unsigned)HH && (unsigned)gw < (unsigned)WW)
                    v = xc[c * IMG + gh * WW + gw];
                xs[i] = v;
            }
        }
        __syncthreads();

        const float* xp0 = xs + ph * HALO_W + pw;
        #pragma unroll 4
        for (int c = 0; c < CG; ++c) {
            const float* xp = xp0 + c * CH_STRIDE;
            float xv[9];
            #pragma unroll
            for (int kh = 0; kh < 3; ++kh)
                #pragma unroll
                for (int kw = 0; kw < 3; ++kw)
                    xv[kh * 3 + kw] = xp[kh * HALO_W + kw];
            #pragma unroll
            for (int oo = 0; oo < OT; ++oo) {
                const float* wp = wb + (oo * CIN + cg + c) * 9;  // uniform
                #pragma unroll
                for (int t = 0; t < 9; ++t)
                    acc[oo] += fminf(xv[t], wp[t]);
            }
        }
    }

    const float mu = ws[0] * (1.0f / (float)NW);
    float* ob = out + (b * OCH + o0) * IMG + (h0 + ph) * WW + pw;
    #pragma unroll
    for (int oo = 0; oo < OT; ++oo)
        ob[oo * IMG] = mu * acc[oo];
}

extern "C" void kernel_launch(void* const* d_in, const int* in_sizes, int n_in,
                              void* d_out, int out_size, void* d_ws, size_t ws_size,
                              hipStream_t stream) {
    const float* x   = (const float*)d_in[0];   // 4*32*56*56
    const float* w   = (const float*)d_in[1];   // 64*32*3*3
    float*       out = (float*)d_out;           // 4*64*56*56
    float*       ws  = (float*)d_ws;

    hipMemsetAsync(ws, 0, sizeof(float), stream);
    absmean_reduce<<<NW / (256 * 4), 256, 0, stream>>>(w, ws);
    dim3 grid(HH / TH, OCH / OT, BB);           // 7 x 16 x 4 = 448 blocks
    minconv_kernel<<<grid, NT, 0, stream>>>(x, w, ws, out);
}